// Round 2
// 3739.477 us; speedup vs baseline: 1.0191x; 1.0191x over previous
//
#include <hip/hip_runtime.h>

#define B_ 256
#define S_ 512
#define E_ 128
#define H_ 256
#define FH_ 1024
#define HROW 264  // 256 + 8 pad (shorts) -> row offset 132 dwords = 4 mod 32, conflict-free

typedef __bf16 bf16x8 __attribute__((ext_vector_type(8)));
typedef float f32x4 __attribute__((ext_vector_type(4)));
typedef unsigned short u16x4 __attribute__((ext_vector_type(4)));
typedef unsigned short u16x8 __attribute__((ext_vector_type(8)));

__device__ __forceinline__ unsigned short f2bf(float f) {
  union { float f; unsigned int u; } a; a.f = f;
  unsigned int u = a.u;
  u += 0x7fffu + ((u >> 16) & 1u);  // RNE
  return (unsigned short)(u >> 16);
}
__device__ __forceinline__ float bf2f(unsigned short v) {
  union { unsigned int u; float f; } a; a.u = ((unsigned int)v) << 16;
  return a.f;
}
__device__ __forceinline__ float sigm(float x) { return 1.f / (1.f + __expf(-x)); }
__device__ __forceinline__ float tanh_(float x) {
  float e = __expf(2.f * x);
  return 1.f - 2.f / (e + 1.f);
}

// ---------------- workspace layout (bytes) ----------------
#define OFF_ENC    ((size_t)0)          // enc_out bf16 [256][512][256]  67108864
#define OFF_WHHE   ((size_t)67108864)   // enc_Whh bf16 [1024][256]        524288
#define OFF_WHHP   ((size_t)67633152)   // pb_Whh  bf16                    524288
#define OFF_WREF   ((size_t)68157440)   // Wref    bf16 [256][256]         131072
#define OFF_MENC   ((size_t)68288512)   // M = enc_Wih@W_emb f32 [1024][2]   8192
#define OFF_BIASE  ((size_t)68296704)   // enc_bih+enc_bhh f32 [1024]        4096
#define OFF_XPV    ((size_t)68300800)   // pb x-projection f32 [1024]        4096
#define OFF_FLAGS  ((size_t)68304896)   // u32 flags                         1024
#define OFF_HX     ((size_t)68305920)   // h exchange bf16 [2][16][2][16][128] 262144
#define OFF_HFIN   ((size_t)68568064)   // final h f32 [256][256]          262144
#define OFF_QBUF   ((size_t)68830208)   // q f32 [256][256]                262144
#define OFF_UBUF   ((size_t)69092352)   // u f32 [256][512]                524288

// ---------------- K0: prep (weight conversion, folded projections, zeroing) ----
__global__ void k0_prep(const float* __restrict__ eWih, const float* __restrict__ eWhh,
                        const float* __restrict__ ebih, const float* __restrict__ ebhh,
                        const float* __restrict__ pWih, const float* __restrict__ pWhh,
                        const float* __restrict__ pbih, const float* __restrict__ pbhh,
                        const float* __restrict__ W_emb, const float* __restrict__ dec_in,
                        const float* __restrict__ Wref,
                        unsigned short* __restrict__ WhhE, unsigned short* __restrict__ WhhP,
                        unsigned short* __restrict__ Wrefb,
                        float* __restrict__ Menc, float* __restrict__ biasE,
                        float* __restrict__ xpv,
                        unsigned int* __restrict__ flags, float* __restrict__ ubuf) {
  int gid = blockIdx.x * blockDim.x + threadIdx.x;
  int NT = gridDim.x * blockDim.x;
  for (int i = gid; i < FH_ * H_; i += NT) {
    WhhE[i] = f2bf(eWhh[i]);
    WhhP[i] = f2bf(pWhh[i]);
  }
  for (int i = gid; i < H_ * H_; i += NT) Wrefb[i] = f2bf(Wref[i]);
  for (int i = gid; i < B_ * S_; i += NT) ubuf[i] = 0.f;
  if (gid < 256) flags[gid] = 0u;
  if (gid < FH_) {
    int n = gid;
    float m0 = 0.f, m1 = 0.f, xs = 0.f;
    for (int e = 0; e < E_; ++e) {
      float w = eWih[n * E_ + e];
      m0 += w * W_emb[e * 2 + 0];
      m1 += w * W_emb[e * 2 + 1];
      xs += pWih[n * E_ + e] * dec_in[e];
    }
    Menc[n * 2 + 0] = m0;
    Menc[n * 2 + 1] = m1;
    biasE[n] = ebih[n] + ebhh[n];
    xpv[n] = xs + pbih[n] + pbhh[n];
  }
}

// ---------------- K1: persistent dual-LSTM recurrence ----------------
// 32 WGs x 512 threads. Group = 16 batch rows; pair of WGs (halves) split the
// 1024 gate columns; each WG's Whh half slice resident in VGPRs.
// Weights are loaded through a VOLATILE pointer: a volatile load cannot be
// rematerialized, so the 128 VGPRs of Bf MUST stay live across the step loop.
// (Previous build: VGPR_Count=108 < 128 -> compiler re-loaded all weights from
// global every step = 8 MB/step L2 traffic = the 6 GB FETCH_SIZE / 3.7 ms.)
// Handshake: proven release/acquire protocol (unchanged from passing baseline).
__launch_bounds__(512, 2)
__global__ void k1_lstm(const float* __restrict__ inp,
                        const unsigned short* __restrict__ WhhE,
                        const unsigned short* __restrict__ WhhP,
                        const float* __restrict__ Menc, const float* __restrict__ biasE,
                        const float* __restrict__ xpv,
                        unsigned short* __restrict__ enc_out,
                        unsigned short* __restrict__ hx,
                        unsigned int* __restrict__ flags,
                        float* __restrict__ hfin) {
  __shared__ unsigned short hbuf[16 * HROW];  // h bf16, 16 rows x (256+pad)
  __shared__ float xin[16][2];
  const int tid = threadIdx.x;
  const int wave = tid >> 6, lane = tid & 63, quad = lane >> 4, l16 = lane & 15;
  const int blk = blockIdx.x;
  const int grp = (blk & 7) | ((blk >> 4) << 3);  // 0..15
  const int half = (blk >> 3) & 1;
  const int kloc = (wave << 4) | l16;    // 0..127 within half
  const int kcol = half * 128 + kloc;    // 0..255 global h-column

  for (int i = tid; i < 16 * HROW; i += 512) hbuf[i] = 0;
  if (tid < 32) xin[tid >> 1][tid & 1] = inp[((grp * 16 + (tid >> 1)) * S_ + 0) * 2 + (tid & 1)];

  float c[4] = {0.f, 0.f, 0.f, 0.f};
  float hreg[4] = {0.f, 0.f, 0.f, 0.f};
  bf16x8 Bf[4][8];
  float m0c[4], m1c[4], bc[4];
  unsigned int* myflag = flags + grp * 2 + half;
  unsigned int* pflag = flags + grp * 2 + (1 - half);
  const f32x4 z4 = {0.f, 0.f, 0.f, 0.f};
  __syncthreads();

  int t = 0;
  for (int phase = 0; phase < 2; ++phase) {
    const unsigned short* W = phase ? WhhP : WhhE;
#pragma unroll
    for (int gg = 0; gg < 4; ++gg) {
      int n = gg * 256 + kcol;
#pragma unroll
      for (int kt = 0; kt < 8; ++kt)
        Bf[gg][kt] = *(volatile const bf16x8*)(W + n * H_ + kt * 32 + quad * 8);
      if (phase == 0) {
        m0c[gg] = Menc[n * 2 + 0]; m1c[gg] = Menc[n * 2 + 1]; bc[gg] = biasE[n];
      } else {
        m0c[gg] = 0.f; m1c[gg] = 0.f; bc[gg] = xpv[n];
      }
    }
    for (int step = 0; step < 512; ++step, ++t) {
      // ---- GEMM: g = h @ Whh^T (this WG's 512 columns) ----
      f32x4 acc[4];
#pragma unroll
      for (int kt = 0; kt < 8; ++kt) {
        bf16x8 Af = *(const bf16x8*)(hbuf + l16 * HROW + kt * 32 + quad * 8);
#pragma unroll
        for (int gg = 0; gg < 4; ++gg)
          acc[gg] = __builtin_amdgcn_mfma_f32_16x16x32_bf16(
              Af, Bf[gg][kt], (kt == 0) ? z4 : acc[gg], 0, 0, 0);
      }
      // ---- gates (fp32). lane holds rows quad*4+r, column kcol, all 4 gates ----
      unsigned short hb[4];
#pragma unroll
      for (int r = 0; r < 4; ++r) {
        int bl = quad * 4 + r;
        float x0 = xin[bl][0], x1 = xin[bl][1];
        float gi = acc[0][r] + x0 * m0c[0] + x1 * m1c[0] + bc[0];
        float gf = acc[1][r] + x0 * m0c[1] + x1 * m1c[1] + bc[1];
        float gc = acc[2][r] + x0 * m0c[2] + x1 * m1c[2] + bc[2];
        float go = acc[3][r] + x0 * m0c[3] + x1 * m1c[3] + bc[3];
        float cn = sigm(gf) * c[r] + sigm(gi) * tanh_(gc);
        c[r] = cn;
        hreg[r] = sigm(go) * tanh_(cn);
        hb[r] = f2bf(hreg[r]);
      }
      // ---- publish own half (global) ----
      if (phase == 0) {
#pragma unroll
        for (int r = 0; r < 4; ++r)
          enc_out[(((size_t)(grp * 16 + quad * 4 + r) * S_ + step)) * H_ + kcol] = hb[r];
      }
      {
        unsigned short* hxs = hx + ((size_t)((t & 1) * 32 + grp * 2 + half)) * 2048;
#pragma unroll
        for (int r = 0; r < 4; ++r) hxs[(quad * 4 + r) * 128 + kloc] = hb[r];
      }
      __syncthreads();  // (a) A-frag reads done; hx stores drained
      if (tid == 0) {
        __hip_atomic_store(myflag, (unsigned int)(t + 1), __ATOMIC_RELEASE,
                           __HIP_MEMORY_SCOPE_AGENT);
        while (__hip_atomic_load(pflag, __ATOMIC_ACQUIRE, __HIP_MEMORY_SCOPE_AGENT) <
               (unsigned int)(t + 1)) {
          __builtin_amdgcn_s_sleep(1);
        }
      }
      __syncthreads();  // (b)
      // ---- update LDS h: own half from regs, peer half from hx ----
#pragma unroll
      for (int r = 0; r < 4; ++r) hbuf[(quad * 4 + r) * HROW + kcol] = hb[r];
      {
        const unsigned short* ph = hx + ((size_t)((t & 1) * 32 + grp * 2 + (1 - half))) * 2048;
        int idx = tid * 4;  // 0..2047
        int prow = idx >> 7, pcol = idx & 127;
        u16x4 v = *(const u16x4*)(ph + idx);
        *(u16x4*)(hbuf + prow * HROW + (1 - half) * 128 + pcol) = v;
      }
      if (phase == 0 && step < 511 && tid < 32)
        xin[tid >> 1][tid & 1] =
            inp[((grp * 16 + (tid >> 1)) * S_ + (step + 1)) * 2 + (tid & 1)];
      __syncthreads();  // (c) h ready for next step
    }
  }
  // final h (fp32) for the attention query
#pragma unroll
  for (int r = 0; r < 4; ++r)
    hfin[(grp * 16 + quad * 4 + r) * H_ + kcol] = hreg[r];
}

// ---------------- K1b: q = h @ Wq^T + bq (fp32) ----------------
__global__ void k1b_q(const float* __restrict__ hfin, const float* __restrict__ Wq,
                      const float* __restrict__ bq, float* __restrict__ qbuf) {
  __shared__ float hl[H_];
  int b = blockIdx.x, j = threadIdx.x;
  hl[j] = hfin[b * H_ + j];
  __syncthreads();
  float s = bq[j];
  const float* w = Wq + j * H_;
  for (int k = 0; k < H_; ++k) s += hl[k] * w[k];
  qbuf[b * H_ + j] = s;
}

// ---------------- K2: u = tanh(enc_out@Wref^T + bref + q) @ V (fused) ----------
__launch_bounds__(512)
__global__ void k2_att(const unsigned short* __restrict__ enc_out,
                       const unsigned short* __restrict__ Wrefb,
                       const float* __restrict__ qbuf, const float* __restrict__ bref,
                       const float* __restrict__ V, float* __restrict__ ubuf) {
  __shared__ unsigned short Bs[128 * HROW];
  __shared__ float qs[128], Vs[128];
  int tid = threadIdx.x;
  int wave = tid >> 6, lane = tid & 63, quad = lane >> 4, l16 = lane & 15;
  int rowblk = blockIdx.x >> 1, nb = blockIdx.x & 1;
  int b = rowblk >> 2;
  {  // stage Wref block [nb*128 .. +128) x 256 into LDS
    int nl = tid >> 2, seg = tid & 3;
    const unsigned short* src = Wrefb + (nb * 128 + nl) * H_ + seg * 64;
    unsigned short* dst = Bs + nl * HROW + seg * 64;
#pragma unroll
    for (int i = 0; i < 8; ++i) *(u16x8*)(dst + i * 8) = *(const u16x8*)(src + i * 8);
  }
  if (tid < 128) {
    int j = nb * 128 + tid;
    qs[tid] = qbuf[b * H_ + j] + bref[j];
    Vs[tid] = V[j];
  }
  __syncthreads();
  int rw = rowblk * 128 + wave * 16 + l16;  // global (b,s) row
  const f32x4 z4 = {0.f, 0.f, 0.f, 0.f};
  f32x4 acc[8];
#pragma unroll
  for (int kt = 0; kt < 8; ++kt) {
    bf16x8 af = *(const bf16x8*)(enc_out + (size_t)rw * H_ + kt * 32 + quad * 8);
#pragma unroll
    for (int nt = 0; nt < 8; ++nt) {
      bf16x8 bfr = *(const bf16x8*)(Bs + (nt * 16 + l16) * HROW + kt * 32 + quad * 8);
      acc[nt] = __builtin_amdgcn_mfma_f32_16x16x32_bf16(af, bfr, (kt == 0) ? z4 : acc[nt],
                                                        0, 0, 0);
    }
  }
  float part[4] = {0.f, 0.f, 0.f, 0.f};
#pragma unroll
  for (int nt = 0; nt < 8; ++nt) {
    float qv = qs[nt * 16 + l16], vv = Vs[nt * 16 + l16];
#pragma unroll
    for (int r = 0; r < 4; ++r) part[r] += tanh_(acc[nt][r] + qv) * vv;
  }
#pragma unroll
  for (int m = 1; m < 16; m <<= 1) {
#pragma unroll
    for (int r = 0; r < 4; ++r) part[r] += __shfl_xor(part[r], m, 64);
  }
  if (l16 == 0) {
    int s0 = (rowblk & 3) * 128 + wave * 16 + quad * 4;
#pragma unroll
    for (int r = 0; r < 4; ++r) atomicAdd(&ubuf[b * S_ + s0 + r], part[r]);
  }
}

// ---------------- K3: softmax + glimpse + decoder head ----------------
__global__ void k3_head(const float* __restrict__ ubuf,
                        const unsigned short* __restrict__ enc_out,
                        const float* __restrict__ Wd1, const float* __restrict__ Wd2,
                        float* __restrict__ out) {
  __shared__ float sm[512];
  __shared__ float red[256];
  __shared__ float gl[256];
  int b = blockIdx.x, tid = threadIdx.x;
  float u0 = ubuf[b * S_ + tid], u1 = ubuf[b * S_ + 256 + tid];
  red[tid] = fmaxf(u0, u1);
  __syncthreads();
  for (int s = 128; s > 0; s >>= 1) {
    if (tid < s) red[tid] = fmaxf(red[tid], red[tid + s]);
    __syncthreads();
  }
  float mx = red[0];
  __syncthreads();
  float e0 = __expf(u0 - mx), e1 = __expf(u1 - mx);
  red[tid] = e0 + e1;
  __syncthreads();
  for (int s = 128; s > 0; s >>= 1) {
    if (tid < s) red[tid] += red[tid + s];
    __syncthreads();
  }
  float inv = 1.f / red[0];
  sm[tid] = e0 * inv;
  sm[256 + tid] = e1 * inv;
  __syncthreads();
  float g = 0.f;
  const unsigned short* eo = enc_out + (size_t)b * S_ * H_ + tid;
  for (int s = 0; s < S_; ++s) g += sm[s] * bf2f(eo[(size_t)s * H_]);
  gl[tid] = g;
  __syncthreads();
  float y = 0.f;
  const float* w = Wd1 + tid * H_;
  for (int j = 0; j < H_; ++j) y += w[j] * gl[j];
  y = fmaxf(y, 0.f) * Wd2[tid];
  red[tid] = y;
  __syncthreads();
  for (int s = 128; s > 0; s >>= 1) {
    if (tid < s) red[tid] += red[tid + s];
    __syncthreads();
  }
  if (tid == 0) out[b] = red[0];
}

extern "C" void kernel_launch(void* const* d_in, const int* in_sizes, int n_in,
                              void* d_out, int out_size, void* d_ws, size_t ws_size,
                              hipStream_t stream) {
  (void)in_sizes; (void)n_in; (void)out_size; (void)ws_size;
  const float* inp    = (const float*)d_in[0];
  const float* W_emb  = (const float*)d_in[1];
  const float* dec_in = (const float*)d_in[2];
  const float* eWih   = (const float*)d_in[3];
  const float* eWhh   = (const float*)d_in[4];
  const float* ebih   = (const float*)d_in[5];
  const float* ebhh   = (const float*)d_in[6];
  const float* pWih   = (const float*)d_in[7];
  const float* pWhh   = (const float*)d_in[8];
  const float* pbih   = (const float*)d_in[9];
  const float* pbhh   = (const float*)d_in[10];
  const float* Wq     = (const float*)d_in[11];
  const float* bq     = (const float*)d_in[12];
  const float* Wref   = (const float*)d_in[13];
  const float* bref   = (const float*)d_in[14];
  const float* V      = (const float*)d_in[15];
  const float* Wd1    = (const float*)d_in[16];
  const float* Wd2    = (const float*)d_in[17];
  float* out = (float*)d_out;

  char* ws = (char*)d_ws;
  unsigned short* enc_out = (unsigned short*)(ws + OFF_ENC);
  unsigned short* WhhE    = (unsigned short*)(ws + OFF_WHHE);
  unsigned short* WhhP    = (unsigned short*)(ws + OFF_WHHP);
  unsigned short* Wrefb   = (unsigned short*)(ws + OFF_WREF);
  float* Menc  = (float*)(ws + OFF_MENC);
  float* biasE = (float*)(ws + OFF_BIASE);
  float* xpv   = (float*)(ws + OFF_XPV);
  unsigned int* flags = (unsigned int*)(ws + OFF_FLAGS);
  unsigned short* hx  = (unsigned short*)(ws + OFF_HX);
  float* hfin = (float*)(ws + OFF_HFIN);
  float* qbuf = (float*)(ws + OFF_QBUF);
  float* ubuf = (float*)(ws + OFF_UBUF);

  hipLaunchKernelGGL(k0_prep, dim3(256), dim3(256), 0, stream,
                     eWih, eWhh, ebih, ebhh, pWih, pWhh, pbih, pbhh, W_emb, dec_in,
                     Wref, WhhE, WhhP, Wrefb, Menc, biasE, xpv, flags, ubuf);
  hipLaunchKernelGGL(k1_lstm, dim3(32), dim3(512), 0, stream,
                     inp, WhhE, WhhP, Menc, biasE, xpv, enc_out, hx, flags, hfin);
  hipLaunchKernelGGL(k1b_q, dim3(256), dim3(256), 0, stream, hfin, Wq, bq, qbuf);
  hipLaunchKernelGGL(k2_att, dim3(2048), dim3(512), 0, stream,
                     enc_out, Wrefb, qbuf, bref, V, ubuf);
  hipLaunchKernelGGL(k3_head, dim3(256), dim3(256), 0, stream,
                     ubuf, enc_out, Wd1, Wd2, out);
}